// Round 3
// baseline (104.605 us; speedup 1.0000x reference)
//
#include <hip/hip_runtime.h>

#define NN   2048
#define IN   64
#define HID  32
#define OUTD 16

// Fully-fused single kernel.  Dataflow:
//   s0=colsum(x) -> agg1 -> h1=relu(x@W1+agg1) -> s1=colsum(h1)
//   -> out = h1@loop_w2 + (bias2 + s1@W2c)
// The two global reductions are tiny (64 / 32 floats).  Instead of 3 dispatches
// (R2: 88.3us) we use flag-based grid barriers: 64 blocks <= 256 CUs are always
// co-resident, so a release/acquire semaphore is deadlock-free and cheaper than
// two dispatch boundaries.  h1 and out_part never touch global memory.
//
// Barrier protocol is INIT-FREE (works under any ws poison value):
//   - block b clears f1[b] BEFORE its release of f0[b]; any reader of f1 has
//     passed barrier-0 (acquired f0[b]=MAGIC), so it can never observe a stale
//     MAGIC in f1 from a previous launch.
//   - f0[b] is cleared after barrier-1 (all blocks provably done reading f0),
//     leaving it non-MAGIC for the next launch.
//   - release = __threadfence() + relaxed store; acquire = relaxed spin +
//     __threadfence().  Agent-scope fences handle cross-XCD L2 coherence.
//
// ws layout (floats):
//   [S0P, S0P+64*64) : per-block partial colsums of x
//   [S1P, S1P+64*32) : per-block partial colsums of h1
//   [F0W, F0W+64)    : barrier-0 flags (uint32)
//   [F1W, F1W+64)    : barrier-1 flags (uint32)
#define S0P 0
#define S1P 4096
#define F0W 6144
#define F1W 6208
#define MAGIC 0x3C0FFEE1u

__global__ __launch_bounds__(256) void k_fused(const float* __restrict__ x,
                                               const float* __restrict__ bases1,
                                               const float* __restrict__ coeff1,
                                               const float* __restrict__ loop_w1,
                                               const float* __restrict__ bias1,
                                               const float* __restrict__ bases2,
                                               const float* __restrict__ coeff2,
                                               const float* __restrict__ loop_w2,
                                               const float* __restrict__ bias2,
                                               float* __restrict__ ws,
                                               float* __restrict__ out) {
    __shared__ float  xsh[32 * IN];       // 8 KB
    __shared__ float  w1sh[IN * HID];     // 8 KB
    __shared__ float  b1sh[IN * HID];     // 8 KB (bases1)
    __shared__ float  w2sh[HID * OUTD];   // 2 KB (loop_w2)
    __shared__ float  w2csh[HID * OUTD];  // 2 KB (sum_r coeff2[0,r]*bases2[r])
    __shared__ float  h1sh[32 * 33];      // 4.2 KB, +1 pad
    __shared__ float4 red4[256];          // 4 KB
    __shared__ float  red[256];           // 1 KB
    __shared__ float  s0sh[IN];
    __shared__ float  agg1sh[HID];
    __shared__ float  s1sh[HID];
    __shared__ float  agg2sh[OUTD];
    const int tid = threadIdx.x, b = blockIdx.x;   // 64 blocks x 32 rows
    uint32_t* f0 = (uint32_t*)ws + F0W;
    uint32_t* f1 = (uint32_t*)ws + F1W;

    // self-init: clear own barrier-1 flag before the barrier-0 release below.
    if (tid == 0)
        __hip_atomic_store(&f1[b], 0u, __ATOMIC_RELAXED, __HIP_MEMORY_SCOPE_AGENT);

    // ---- stage everything independent of the barriers (overlaps exchange) ----
    const float4* x4  = (const float4*)(x + b * 32 * IN);
    const float4* w14 = (const float4*)loop_w1;
    const float4* b14 = (const float4*)bases1;
    float4 xa = x4[tid], xb = x4[tid + 256];       // rows tid>>4 and (tid>>4)+16
    float4 wa = w14[tid], wb = w14[tid + 256];
    float4 ba = b14[tid], bb = b14[tid + 256];
    float4 w2v = {0.f, 0.f, 0.f, 0.f};
    if (tid < 128) w2v = ((const float4*)loop_w2)[tid];

    ((float4*)xsh)[tid]  = xa; ((float4*)xsh)[tid + 256]  = xb;
    ((float4*)w1sh)[tid] = wa; ((float4*)w1sh)[tid + 256] = wb;
    ((float4*)b1sh)[tid] = ba; ((float4*)b1sh)[tid + 256] = bb;
    if (tid < 128) ((float4*)w2sh)[tid] = w2v;
    {   // combined basis for layer 2 (weights only, no data dependence)
        const float c20 = coeff2[0], c21 = coeff2[1], c22 = coeff2[2], c23 = coeff2[3];
#pragma unroll
        for (int j = 0; j < 2; ++j) {
            const int i = tid + j * 256;
            w2csh[i] = c20 * bases2[i]        + c21 * bases2[512 + i] +
                       c22 * bases2[1024 + i] + c23 * bases2[1536 + i];
        }
    }

    // ---- phase 1: per-block partial colsum of own 32 rows (from registers) ----
    {
        float4 p;
        p.x = xa.x + xb.x; p.y = xa.y + xb.y; p.z = xa.z + xb.z; p.w = xa.w + xb.w;
        red4[tid] = p;                             // [r=tid>>4][q=tid&15] == tid
    }
    __syncthreads();
    if (tid < 16) {                                // quad-col tid: sum 16 row pairs
        float4 t = {0.f, 0.f, 0.f, 0.f};
#pragma unroll
        for (int r = 0; r < 16; ++r) {
            float4 v = red4[r * 16 + tid];
            t.x += v.x; t.y += v.y; t.z += v.z; t.w += v.w;
        }
        ((float4*)(ws + S0P + b * 64))[tid] = t;
    }
    __syncthreads();                               // drains vmem before barrier
    __threadfence();                               // release (agent scope)
    if (tid == 0)
        __hip_atomic_store(&f0[b], MAGIC, __ATOMIC_RELAXED, __HIP_MEMORY_SCOPE_AGENT);

    // ---- grid barrier 0 ----
    if (tid < 64)
        while (__hip_atomic_load(&f0[tid], __ATOMIC_RELAXED,
                                 __HIP_MEMORY_SCOPE_AGENT) != MAGIC)
            __builtin_amdgcn_s_sleep(1);
    __syncthreads();
    __threadfence();                               // acquire (invalidate stale)

    // ---- s0 = total colsum of x (reduce 64x64 partials) ----
    {
        const int col = tid & 63, g = tid >> 6;    // g sums blocks 16g..16g+15
        float a0 = 0.f, a1 = 0.f, a2 = 0.f, a3 = 0.f;
#pragma unroll
        for (int k = 0; k < 4; ++k) {
            a0 += ws[S0P + (g * 16 + k     ) * 64 + col];
            a1 += ws[S0P + (g * 16 + 4 + k ) * 64 + col];
            a2 += ws[S0P + (g * 16 + 8 + k ) * 64 + col];
            a3 += ws[S0P + (g * 16 + 12 + k) * 64 + col];
        }
        red[tid] = a0 + a1 + a2 + a3;
    }
    __syncthreads();
    if (tid < 64)
        s0sh[tid] = red[tid] + red[tid + 64] + red[tid + 128] + red[tid + 192];
    __syncthreads();

    // ---- agg1[h] = bias1[h] + c1 * sum_k s0[k]*bases1[k*HID+h] ----
    {
        const int h = tid & 31, seg = tid >> 5;
        float p = 0.f;
#pragma unroll
        for (int k = 0; k < 8; ++k)
            p += s0sh[seg * 8 + k] * b1sh[(seg * 8 + k) * HID + h];
        red[tid] = p;
        __syncthreads();
        if (tid < HID) {
            float t = 0.f;
#pragma unroll
            for (int g = 0; g < 8; ++g) t += red[g * 32 + tid];
            agg1sh[tid] = bias1[tid] + coeff1[0] * t;
        }
    }
    __syncthreads();

    // ---- h1 for 32 rows + s1 partial ----
    {
        const int h = tid & 31, rgrp = tid >> 5;
        const float agg1v = agg1sh[h];
        float a0 = agg1v, a1 = agg1v, a2 = agg1v, a3 = agg1v;
#pragma unroll
        for (int k = 0; k < IN; ++k) {
            const float w = w1sh[k * HID + h];     // broadcast within wave
            a0 += xsh[(rgrp +  0) * IN + k] * w;
            a1 += xsh[(rgrp +  8) * IN + k] * w;
            a2 += xsh[(rgrp + 16) * IN + k] * w;
            a3 += xsh[(rgrp + 24) * IN + k] * w;
        }
        a0 = fmaxf(a0, 0.f); a1 = fmaxf(a1, 0.f);
        a2 = fmaxf(a2, 0.f); a3 = fmaxf(a3, 0.f);
        h1sh[(rgrp +  0) * 33 + h] = a0;
        h1sh[(rgrp +  8) * 33 + h] = a1;
        h1sh[(rgrp + 16) * 33 + h] = a2;
        h1sh[(rgrp + 24) * 33 + h] = a3;
        red[tid] = a0 + a1 + a2 + a3;              // partial s1
    }
    __syncthreads();
    if (tid < HID) {
        float t = 0.f;
#pragma unroll
        for (int g = 0; g < 8; ++g) t += red[g * 32 + tid];
        ws[S1P + b * HID + tid] = t;
    }
    __syncthreads();                               // drains vmem
    __threadfence();                               // release
    if (tid == 0)
        __hip_atomic_store(&f1[b], MAGIC, __ATOMIC_RELAXED, __HIP_MEMORY_SCOPE_AGENT);

    // ---- out_part = h1 @ loop_w2, kept in registers (overlaps barrier 1) ----
    const int r0 = tid >> 4, o = tid & 15;         // rows r0, r0+16
    float acc0 = 0.f, acc1 = 0.f;
#pragma unroll
    for (int h = 0; h < HID; ++h) {
        const float w = w2sh[h * OUTD + o];        // broadcast within wave
        acc0 += h1sh[(r0     ) * 33 + h] * w;
        acc1 += h1sh[(r0 + 16) * 33 + h] * w;
    }

    // ---- grid barrier 1 ----
    if (tid < 64)
        while (__hip_atomic_load(&f1[tid], __ATOMIC_RELAXED,
                                 __HIP_MEMORY_SCOPE_AGENT) != MAGIC)
            __builtin_amdgcn_s_sleep(1);
    __syncthreads();
    __threadfence();                               // acquire

    // ---- s1 total + agg2 ----
    {
        const int h = tid & 31, g = tid >> 5;      // g sums 8 blocks
        float a0 = 0.f, a1 = 0.f;
#pragma unroll
        for (int k = 0; k < 4; ++k) {
            a0 += ws[S1P + (g * 8 + k    ) * HID + h];
            a1 += ws[S1P + (g * 8 + 4 + k) * HID + h];
        }
        red[tid] = a0 + a1;
    }
    __syncthreads();
    if (tid < HID) {
        float t = 0.f;
#pragma unroll
        for (int g = 0; g < 8; ++g) t += red[g * 32 + tid];
        s1sh[tid] = t;
    }
    __syncthreads();
    if (tid < OUTD) {
        float s = 0.f;
#pragma unroll
        for (int h = 0; h < HID; ++h) s += s1sh[h] * w2csh[h * OUTD + tid];
        agg2sh[tid] = bias2[tid] + s;
    }
    __syncthreads();

    // ---- final store (out written exactly once) ----
    out[b * 512 + tid]       = acc0 + agg2sh[o];
    out[b * 512 + 256 + tid] = acc1 + agg2sh[o];

    // leave f0 non-MAGIC for the next launch (all readers provably done)
    if (tid == 0)
        __hip_atomic_store(&f0[b], 0u, __ATOMIC_RELAXED, __HIP_MEMORY_SCOPE_AGENT);
}

extern "C" void kernel_launch(void* const* d_in, const int* in_sizes, int n_in,
                              void* d_out, int out_size, void* d_ws, size_t ws_size,
                              hipStream_t stream) {
    const float* x       = (const float*)d_in[0];
    // d_in[1] = adj_matrix: mathematically unused (complete graph w/ self-loops)
    const float* bases1  = (const float*)d_in[2];
    const float* coeff1  = (const float*)d_in[3];
    const float* loop_w1 = (const float*)d_in[4];
    const float* bias1   = (const float*)d_in[5];
    const float* bases2  = (const float*)d_in[6];
    const float* coeff2  = (const float*)d_in[7];
    const float* loop_w2 = (const float*)d_in[8];
    const float* bias2   = (const float*)d_in[9];
    float* out = (float*)d_out;
    float* ws  = (float*)d_ws;

    k_fused<<<64, 256, 0, stream>>>(x, bases1, coeff1, loop_w1, bias1,
                                    bases2, coeff2, loop_w2, bias2, ws, out);
}

// Round 4
// 97.052 us; speedup vs baseline: 1.0778x; 1.0778x over previous
//
#include <hip/hip_runtime.h>

#define NN   2048
#define IN   64
#define HID  32
#define OUTD 16

// Dataflow: s0=colsum(x) -> agg1 -> h1=relu(x@W1+agg1) -> s1=colsum(h1)
//           -> out = h1@loop_w2 + (bias2 + s1@W2c)
// Sync structure (measured across R0-R3):
//   - s0 is an all-to-all dependency -> needs a dispatch boundary (k1|k2).
//     Full grid barriers measured +8us each (R3); block-redundant colsum
//     measured worse (R1).  Dispatch boundary wins.
//   - s1 -> agg2 -> out+=agg2 is MANY-TO-ONE: only the agg2 computer needs
//     all partials.  A last-block-done ticket (one atomicAdd, no spinning,
//     63 blocks exit immediately) absorbs k3 into k2's tail, saving k3's
//     launch + gap.  h1 and out_part never touch global memory.
//
// ws layout (floats) — every slot write-before-read (0xAA poison harmless):
//   [S0P, S0P+64*64) : k1 per-block partial colsums of x   (64 blocks x 64)
//   [S1P, S1P+64*32) : k2 per-block partial colsums of h1  (64 blocks x 32)
//   [TKT]            : uint32 done-ticket, zeroed by k1 before k2 runs
#define S0P 0
#define S1P 4096
#define TKT 6144

// ---------------------------------------------------------------- k1 -------
__global__ __launch_bounds__(256) void k1_colsum_x(const float* __restrict__ x,
                                                   float* __restrict__ ws) {
    __shared__ float red[256];
    const int tid = threadIdx.x, b = blockIdx.x;   // 64 blocks x 32 rows
    if (b == 0 && tid == 0)                         // init ticket for k2
        __hip_atomic_store((uint32_t*)ws + TKT, 0u,
                           __ATOMIC_RELAXED, __HIP_MEMORY_SCOPE_AGENT);
    const int col = tid & 63, grp = tid >> 6;      // 4 groups x 8 rows
    const float* xb = x + b * 32 * IN;
    float s = 0.f;
#pragma unroll
    for (int r = 0; r < 8; ++r)                    // 8 independent coalesced loads
        s += xb[(grp * 8 + r) * IN + col];
    red[tid] = s;
    __syncthreads();
    if (tid < 64)
        ws[S0P + b * 64 + tid] = red[tid] + red[tid + 64] + red[tid + 128] + red[tid + 192];
}

// ---------------------------------------------------------------- k2 -------
__global__ __launch_bounds__(256) void k2_fused(const float* __restrict__ x,
                                                const float* __restrict__ bases1,
                                                const float* __restrict__ coeff1,
                                                const float* __restrict__ loop_w1,
                                                const float* __restrict__ bias1,
                                                const float* __restrict__ bases2,
                                                const float* __restrict__ coeff2,
                                                const float* __restrict__ loop_w2,
                                                const float* __restrict__ bias2,
                                                float* __restrict__ ws,
                                                float* __restrict__ out) {
    __shared__ float w1sh[IN * HID];        // 8 KB
    __shared__ float xsh[32 * IN];          // 8 KB
    __shared__ float w2sh[HID * OUTD];      // 2 KB  (loop_w2)
    __shared__ float w2csh[HID * OUTD];     // 2 KB  (sum_r coeff2[0,r]*bases2[r])
    __shared__ float h1sh[32 * 33];         // 4.2 KB, +1 pad
    __shared__ float s0sh[IN];
    __shared__ float agg1sh[HID];
    __shared__ float s1sh[HID];
    __shared__ float agg2sh[OUTD];
    __shared__ float red[256];
    __shared__ uint32_t last_sh;
    const int tid = threadIdx.x, b = blockIdx.x;   // 64 blocks x 32 rows
    uint32_t* tkt = (uint32_t*)ws + TKT;

    // stage own x tile + w1 + w2 + combined basis (all independent, issue early)
    const float4* x4  = (const float4*)(x + b * 32 * IN);
    const float4* w14 = (const float4*)loop_w1;
    float4 xa = x4[tid], xb4 = x4[tid + 256];
    float4 wa = w14[tid], wb = w14[tid + 256];
    float4 w2v = {0.f, 0.f, 0.f, 0.f};
    if (tid < 128) w2v = ((const float4*)loop_w2)[tid];
    {
        const float c20 = coeff2[0], c21 = coeff2[1], c22 = coeff2[2], c23 = coeff2[3];
#pragma unroll
        for (int j = 0; j < 2; ++j) {
            const int i = tid + j * 256;
            w2csh[i] = c20 * bases2[i]        + c21 * bases2[512 + i] +
                       c22 * bases2[1024 + i] + c23 * bases2[1536 + i];
        }
    }

    // reduce s0 partials (64 x 64) — 16 independent L2-hot loads per thread
    {
        const int col = tid & 63, g = tid >> 6;    // g sums blocks 16g..16g+15
        float a0 = 0.f, a1 = 0.f, a2 = 0.f, a3 = 0.f;
#pragma unroll
        for (int k = 0; k < 4; ++k) {
            a0 += ws[S0P + (g * 16 + k     ) * 64 + col];
            a1 += ws[S0P + (g * 16 + 4 + k ) * 64 + col];
            a2 += ws[S0P + (g * 16 + 8 + k ) * 64 + col];
            a3 += ws[S0P + (g * 16 + 12 + k) * 64 + col];
        }
        ((float4*)xsh)[tid] = xa; ((float4*)xsh)[tid + 256] = xb4;
        ((float4*)w1sh)[tid] = wa; ((float4*)w1sh)[tid + 256] = wb;
        if (tid < 128) ((float4*)w2sh)[tid] = w2v;
        red[tid] = a0 + a1 + a2 + a3;
    }
    __syncthreads();
    if (tid < 64)
        s0sh[tid] = red[tid] + red[tid + 64] + red[tid + 128] + red[tid + 192];
    __syncthreads();

    // agg1[h] = bias1[h] + c1 * sum_k s0[k]*bases1[k*HID+h]
    {
        const int h = tid & 31, seg = tid >> 5;
        float p = 0.f;
#pragma unroll
        for (int k = 0; k < 8; ++k)
            p += s0sh[seg * 8 + k] * bases1[(seg * 8 + k) * HID + h];
        red[tid] = p;
        __syncthreads();
        if (tid < HID) {
            float t = 0.f;
#pragma unroll
            for (int g = 0; g < 8; ++g) t += red[g * 32 + tid];
            agg1sh[tid] = bias1[tid] + coeff1[0] * t;
        }
    }
    __syncthreads();

    // h1 for 32 rows: thread = (h = tid&31, rgrp = tid>>5), rows rgrp + {0,8,16,24}
    {
        const int h = tid & 31, rgrp = tid >> 5;
        const float agg1v = agg1sh[h];
        float a0 = agg1v, a1 = agg1v, a2 = agg1v, a3 = agg1v;
#pragma unroll
        for (int k = 0; k < IN; ++k) {
            const float w = w1sh[k * HID + h];     // broadcast within wave
            a0 += xsh[(rgrp +  0) * IN + k] * w;
            a1 += xsh[(rgrp +  8) * IN + k] * w;
            a2 += xsh[(rgrp + 16) * IN + k] * w;
            a3 += xsh[(rgrp + 24) * IN + k] * w;
        }
        a0 = fmaxf(a0, 0.f); a1 = fmaxf(a1, 0.f);
        a2 = fmaxf(a2, 0.f); a3 = fmaxf(a3, 0.f);
        h1sh[(rgrp +  0) * 33 + h] = a0;           // h1 stays on-chip
        h1sh[(rgrp +  8) * 33 + h] = a1;
        h1sh[(rgrp + 16) * 33 + h] = a2;
        h1sh[(rgrp + 24) * 33 + h] = a3;
        red[tid] = a0 + a1 + a2 + a3;              // partial s1
    }
    __syncthreads();
    if (tid < HID) {
        float t = 0.f;
#pragma unroll
        for (int g = 0; g < 8; ++g) t += red[g * 32 + tid];
        ws[S1P + b * HID + tid] = t;
    }
    // out_part = h1 @ loop_w2, straight to out (agg2 added by the last block)
    {
        const int r0 = tid >> 4, o = tid & 15;     // rows r0, r0+16
        float acc0 = 0.f, acc1 = 0.f;
#pragma unroll
        for (int h = 0; h < HID; ++h) {
            const float w = w2sh[h * OUTD + o];    // broadcast within wave
            acc0 += h1sh[(r0     ) * 33 + h] * w;
            acc1 += h1sh[(r0 + 16) * 33 + h] * w;
        }
        out[b * 512 + tid]       = acc0;
        out[b * 512 + 256 + tid] = acc1;
    }

    // ---- last-block-done ticket: many-to-one sync, no spinning ----
    __syncthreads();                               // drains vmem (stores visible in L2)
    if (tid == 0) {
        __threadfence();                           // release (L2 writeback, agent)
        const uint32_t old = __hip_atomic_fetch_add(tkt, 1u, __ATOMIC_ACQ_REL,
                                                    __HIP_MEMORY_SCOPE_AGENT);
        last_sh = (old == 63u);
    }
    __syncthreads();
    if (!last_sh) return;                          // 63 blocks exit immediately
    __threadfence();                               // acquire (invalidate stale)

    // ---- epilogue (one block): s1 total + agg2 + broadcast RMW of out ----
    {
        const int h = tid & 31, g = tid >> 5;      // g sums 8 blocks
        float a0 = 0.f, a1 = 0.f;
#pragma unroll
        for (int k = 0; k < 4; ++k) {
            a0 += ws[S1P + (g * 8 + k    ) * HID + h];
            a1 += ws[S1P + (g * 8 + 4 + k) * HID + h];
        }
        red[tid] = a0 + a1;
    }
    __syncthreads();
    if (tid < HID) {
        float t = 0.f;
#pragma unroll
        for (int g = 0; g < 8; ++g) t += red[g * 32 + tid];
        s1sh[tid] = t;
    }
    __syncthreads();
    if (tid < OUTD) {
        float s = 0.f;
#pragma unroll
        for (int h = 0; h < HID; ++h) s += s1sh[h] * w2csh[h * OUTD + tid];
        agg2sh[tid] = bias2[tid] + s;
    }
    __syncthreads();

    // out += agg2: 8192 float4, 32 per thread, L2-hot, fully independent
    {
        float4* o4 = (float4*)out;
        const int c = (tid & 3) << 2;              // col base of this float4
        const float4 av = { agg2sh[c], agg2sh[c + 1], agg2sh[c + 2], agg2sh[c + 3] };
#pragma unroll 8
        for (int j = 0; j < 32; ++j) {
            float4 v = o4[j * 256 + tid];
            v.x += av.x; v.y += av.y; v.z += av.z; v.w += av.w;
            o4[j * 256 + tid] = v;
        }
    }
}

extern "C" void kernel_launch(void* const* d_in, const int* in_sizes, int n_in,
                              void* d_out, int out_size, void* d_ws, size_t ws_size,
                              hipStream_t stream) {
    const float* x       = (const float*)d_in[0];
    // d_in[1] = adj_matrix: mathematically unused (complete graph w/ self-loops)
    const float* bases1  = (const float*)d_in[2];
    const float* coeff1  = (const float*)d_in[3];
    const float* loop_w1 = (const float*)d_in[4];
    const float* bias1   = (const float*)d_in[5];
    const float* bases2  = (const float*)d_in[6];
    const float* coeff2  = (const float*)d_in[7];
    const float* loop_w2 = (const float*)d_in[8];
    const float* bias2   = (const float*)d_in[9];
    float* out = (float*)d_out;
    float* ws  = (float*)d_ws;

    k1_colsum_x<<<64, 256, 0, stream>>>(x, ws);
    k2_fused  <<<64, 256, 0, stream>>>(x, bases1, coeff1, loop_w1, bias1,
                                       bases2, coeff2, loop_w2, bias2, ws, out);
}

// Round 5
// 90.433 us; speedup vs baseline: 1.1567x; 1.0732x over previous
//
#include <hip/hip_runtime.h>

#define NN   2048
#define IN   64
#define HID  32
#define OUTD 16

// Dataflow: s0=colsum(x) -> agg1 -> h1=relu(x@W1+agg1) -> s1=colsum(h1)
//           -> out = h1@loop_w2 + (bias2 + s1@W2c)
// Sync structure — all alternatives MEASURED worse on this chip:
//   - flag-based grid barriers: +16us (R3; agent-scope fences ~0.13us x blocks)
//   - last-block ticket:        +9us  (R4; 64 release fences + serial tail)
//   - block-redundant colsum:   +8us  (R1; 64-block grid can't hide L2 latency)
//   => dispatch boundaries (~2-3us) are the cheapest grid sync. 3 kernels.
//
// Key split: out = h1@loop_w2 + agg2.  The matmul term needs no global info, so
// k2 computes it from on-chip h1 and writes `out` directly — h1 NEVER goes to
// global memory.  k3 only reduces the tiny s1 partials and RMW-adds the rank-1
// agg2 term onto out.
//
// ws layout (floats) — every slot write-before-read (0xAA poison harmless):
//   [S0P, S0P+64*64) : k1 per-block partial colsums of x   (64 blocks x 64)
//   [S1P, S1P+64*32) : k2 per-block partial colsums of h1  (64 blocks x 32)
#define S0P 0
#define S1P 4096

// ---------------------------------------------------------------- k1 -------
__global__ __launch_bounds__(256) void k1_colsum_x(const float* __restrict__ x,
                                                   float* __restrict__ ws) {
    __shared__ float4 red4[256];
    const int tid = threadIdx.x, b = blockIdx.x;   // 64 blocks x 32 rows
    // float4 pair: rows tid>>4 and (tid>>4)+16, quad tid&15 (validated in R3)
    const float4* x4 = (const float4*)(x + b * 32 * IN);
    const float4 xa = x4[tid], xb = x4[tid + 256];
    float4 p;
    p.x = xa.x + xb.x; p.y = xa.y + xb.y; p.z = xa.z + xb.z; p.w = xa.w + xb.w;
    red4[tid] = p;                                 // [r=tid>>4][q=tid&15]
    __syncthreads();
    if (tid < 16) {                                // quad-col tid: sum 16 row pairs
        float4 t = {0.f, 0.f, 0.f, 0.f};
#pragma unroll
        for (int r = 0; r < 16; ++r) {
            float4 v = red4[r * 16 + tid];
            t.x += v.x; t.y += v.y; t.z += v.z; t.w += v.w;
        }
        ((float4*)(ws + S0P + b * 64))[tid] = t;
    }
}

// ---------------------------------------------------------------- k2 -------
__global__ __launch_bounds__(256) void k2_layer1(const float* __restrict__ x,
                                                 const float* __restrict__ bases1,
                                                 const float* __restrict__ coeff1,
                                                 const float* __restrict__ loop_w1,
                                                 const float* __restrict__ bias1,
                                                 const float* __restrict__ loop_w2,
                                                 float* __restrict__ ws,
                                                 float* __restrict__ out) {
    __shared__ float w1sh[IN * HID];        // 8 KB
    __shared__ float xsh[32 * IN];          // 8 KB
    __shared__ float w2sh[HID * OUTD];      // 2 KB  (loop_w2)
    __shared__ float h1sh[32 * 33];         // 4.2 KB, +1 pad
    __shared__ float s0sh[IN];
    __shared__ float agg1sh[HID];
    __shared__ float red[256];
    const int tid = threadIdx.x, b = blockIdx.x;   // 64 blocks x 32 rows

    // stage own x tile + w1 + w2 (float4, all independent, issue early)
    const float4* x4  = (const float4*)(x + b * 32 * IN);
    const float4* w14 = (const float4*)loop_w1;
    float4 xa = x4[tid], xb4 = x4[tid + 256];
    float4 wa = w14[tid], wb = w14[tid + 256];
    float4 w2v = {0.f, 0.f, 0.f, 0.f};
    if (tid < 128) w2v = ((const float4*)loop_w2)[tid];

    // reduce s0 partials (64 x 64) — 16 independent L2-hot loads per thread
    {
        const int col = tid & 63, g = tid >> 6;    // g sums blocks 16g..16g+15
        float a0 = 0.f, a1 = 0.f, a2 = 0.f, a3 = 0.f;
#pragma unroll
        for (int k = 0; k < 4; ++k) {
            a0 += ws[S0P + (g * 16 + k     ) * 64 + col];
            a1 += ws[S0P + (g * 16 + 4 + k ) * 64 + col];
            a2 += ws[S0P + (g * 16 + 8 + k ) * 64 + col];
            a3 += ws[S0P + (g * 16 + 12 + k) * 64 + col];
        }
        ((float4*)xsh)[tid] = xa; ((float4*)xsh)[tid + 256] = xb4;
        ((float4*)w1sh)[tid] = wa; ((float4*)w1sh)[tid + 256] = wb;
        if (tid < 128) ((float4*)w2sh)[tid] = w2v;
        red[tid] = a0 + a1 + a2 + a3;
    }
    __syncthreads();
    if (tid < 64)
        s0sh[tid] = red[tid] + red[tid + 64] + red[tid + 128] + red[tid + 192];
    __syncthreads();

    // agg1[h] = bias1[h] + c1 * sum_k s0[k]*bases1[k*HID+h]
    {
        const int h = tid & 31, seg = tid >> 5;
        float p = 0.f;
#pragma unroll
        for (int k = 0; k < 8; ++k)
            p += s0sh[seg * 8 + k] * bases1[(seg * 8 + k) * HID + h];
        red[tid] = p;
        __syncthreads();
        if (tid < HID) {
            float t = 0.f;
#pragma unroll
            for (int g = 0; g < 8; ++g) t += red[g * 32 + tid];
            agg1sh[tid] = bias1[tid] + coeff1[0] * t;
        }
    }
    __syncthreads();

    // h1 for 32 rows: thread = (h = tid&31, rgrp = tid>>5), rows rgrp + {0,8,16,24}
    {
        const int h = tid & 31, rgrp = tid >> 5;
        const float agg1v = agg1sh[h];
        float a0 = agg1v, a1 = agg1v, a2 = agg1v, a3 = agg1v;
#pragma unroll
        for (int k = 0; k < IN; ++k) {
            const float w = w1sh[k * HID + h];     // broadcast within wave
            a0 += xsh[(rgrp +  0) * IN + k] * w;
            a1 += xsh[(rgrp +  8) * IN + k] * w;
            a2 += xsh[(rgrp + 16) * IN + k] * w;
            a3 += xsh[(rgrp + 24) * IN + k] * w;
        }
        a0 = fmaxf(a0, 0.f); a1 = fmaxf(a1, 0.f);
        a2 = fmaxf(a2, 0.f); a3 = fmaxf(a3, 0.f);
        // h1 stays on-chip: LDS only (row*33+h is conflict-free both phases)
        h1sh[(rgrp +  0) * 33 + h] = a0;
        h1sh[(rgrp +  8) * 33 + h] = a1;
        h1sh[(rgrp + 16) * 33 + h] = a2;
        h1sh[(rgrp + 24) * 33 + h] = a3;
        red[tid] = a0 + a1 + a2 + a3;              // partial s1
    }
    __syncthreads();
    if (tid < HID) {
        float t = 0.f;
#pragma unroll
        for (int g = 0; g < 8; ++g) t += red[g * 32 + tid];
        ws[S1P + b * HID + tid] = t;
    }
    // out_part = h1 @ loop_w2, straight to out (agg2 added by k3)
    {
        const int r0 = tid >> 4, o = tid & 15;     // rows r0, r0+16
        float acc0 = 0.f, acc1 = 0.f;
#pragma unroll
        for (int h = 0; h < HID; ++h) {
            const float w = w2sh[h * OUTD + o];    // broadcast within wave
            acc0 += h1sh[(r0     ) * 33 + h] * w;
            acc1 += h1sh[(r0 + 16) * 33 + h] * w;
        }
        out[b * 512 + tid]       = acc0;
        out[b * 512 + 256 + tid] = acc1;
    }
}

// ---------------------------------------------------------------- k3 -------
__global__ __launch_bounds__(256) void k3_finish(const float* __restrict__ bases2,
                                                 const float* __restrict__ coeff2,
                                                 const float* __restrict__ bias2,
                                                 const float* __restrict__ ws,
                                                 float* __restrict__ out) {
    __shared__ float w2csh[HID * OUTD];    // sum_r coeff2[0,r]*bases2[r]
    __shared__ float s1sh[HID];
    __shared__ float agg2sh[OUTD];
    __shared__ float red[256];
    const int tid = threadIdx.x, b = blockIdx.x;   // 64 blocks x 128 float4 of out

    // combined basis (2 elements/thread)
    {
        const float c20 = coeff2[0], c21 = coeff2[1], c22 = coeff2[2], c23 = coeff2[3];
#pragma unroll
        for (int j = 0; j < 2; ++j) {
            const int i = tid + j * 256;
            w2csh[i] = c20 * bases2[i]        + c21 * bases2[512 + i] +
                       c22 * bases2[1024 + i] + c23 * bases2[1536 + i];
        }
    }
    // reduce s1 partials (64 x 32, L2-hot): thread (h=tid&31, g=tid>>5) sums 8 blocks
    {
        const int h = tid & 31, g = tid >> 5;
        float a0 = 0.f, a1 = 0.f;
#pragma unroll
        for (int k = 0; k < 4; ++k) {
            a0 += ws[S1P + (g * 8 + k    ) * HID + h];
            a1 += ws[S1P + (g * 8 + 4 + k) * HID + h];
        }
        red[tid] = a0 + a1;
    }
    __syncthreads();
    if (tid < HID) {
        float t = 0.f;
#pragma unroll
        for (int g = 0; g < 8; ++g) t += red[g * 32 + tid];
        s1sh[tid] = t;
    }
    __syncthreads();
    if (tid < OUTD) {
        float s = 0.f;
#pragma unroll
        for (int h = 0; h < HID; ++h) s += s1sh[h] * w2csh[h * OUTD + tid];
        agg2sh[tid] = bias2[tid] + s;
    }
    __syncthreads();

    // out += agg2 (broadcast over rows): 64 blocks x 128 float4 = 128 KB RMW
    if (tid < 128) {
        const int i = b * 128 + tid;               // float4 index into out
        float4 v = ((float4*)out)[i];
        const int c = (tid & 3) << 2;              // col base of this float4
        v.x += agg2sh[c];     v.y += agg2sh[c + 1];
        v.z += agg2sh[c + 2]; v.w += agg2sh[c + 3];
        ((float4*)out)[i] = v;
    }
}

extern "C" void kernel_launch(void* const* d_in, const int* in_sizes, int n_in,
                              void* d_out, int out_size, void* d_ws, size_t ws_size,
                              hipStream_t stream) {
    const float* x       = (const float*)d_in[0];
    // d_in[1] = adj_matrix: mathematically unused (complete graph w/ self-loops)
    const float* bases1  = (const float*)d_in[2];
    const float* coeff1  = (const float*)d_in[3];
    const float* loop_w1 = (const float*)d_in[4];
    const float* bias1   = (const float*)d_in[5];
    const float* bases2  = (const float*)d_in[6];
    const float* coeff2  = (const float*)d_in[7];
    const float* loop_w2 = (const float*)d_in[8];
    const float* bias2   = (const float*)d_in[9];
    float* out = (float*)d_out;
    float* ws  = (float*)d_ws;

    k1_colsum_x<<<64, 256, 0, stream>>>(x, ws);
    k2_layer1 <<<64, 256, 0, stream>>>(x, bases1, coeff1, loop_w1, bias1, loop_w2, ws, out);
    k3_finish <<<64, 256, 0, stream>>>(bases2, coeff2, bias2, ws, out);
}